// Round 2
// baseline (28.001 us; speedup 1.0000x reference)
//
#include <hip/hip_runtime.h>

__device__ __forceinline__ float frcp(float x) { return __builtin_amdgcn_rcpf(x); }

// Solve (2I + 0.3*(cc^T + ss^T)) x = B@u - H for one row, all in registers.
__device__ __forceinline__ void solve_row(const float q[5], const float qd[5],
                                          float u0, float u1, float u2, float u3,
                                          float x[5]) {
    float s[5], c[5];
    #pragma unroll
    for (int i = 0; i < 5; ++i) __sincosf(q[i], &s[i], &c[i]);

    float v2 = qd[0]*qd[0] + qd[1]*qd[1] + qd[2]*qd[2] + qd[3]*qd[3] + qd[4]*qd[4];
    float coef = 0.1f * v2 + 9.8f;

    float bu[5] = {0.f, u0, u1, u2, u3};
    float rhs[5];
    #pragma unroll
    for (int i = 0; i < 5; ++i)
        rhs[i] = bu[i] - (coef * s[i] + 0.05f * qd[i]);

    // D = 2I + 0.3*(c c^T + s s^T)   (cos(qi-qj) = ci*cj + si*sj)
    float D[5][5];
    #pragma unroll
    for (int i = 0; i < 5; ++i) {
        #pragma unroll
        for (int j = 0; j < 5; ++j) {
            float v = 0.3f * (c[i]*c[j] + s[i]*s[j]);
            D[i][j] = (i == j) ? (v + 2.0f) : v;
        }
    }

    // Gaussian elimination, no pivoting (D strictly diagonally dominant).
    // invd[k] saved and reused in back-substitution: 5 rcps total, 0 divides.
    float invd[5];
    #pragma unroll
    for (int k = 0; k < 5; ++k) {
        invd[k] = frcp(D[k][k]);
        #pragma unroll
        for (int r = k + 1; r < 5; ++r) {
            float m = D[r][k] * invd[k];
            #pragma unroll
            for (int cc = k + 1; cc < 5; ++cc)
                D[r][cc] -= m * D[k][cc];
            rhs[r] -= m * rhs[k];
        }
    }
    #pragma unroll
    for (int k = 4; k >= 0; --k) {
        float acc = rhs[k];
        #pragma unroll
        for (int cc = k + 1; cc < 5; ++cc) acc -= D[k][cc] * x[cc];
        x[k] = acc * invd[k];
    }
}

// 2 rows per thread: state/out rows become 5 aligned float4s, u -> 2 float4s.
__global__ __launch_bounds__(256) void amber_dyn2(
    const float4* __restrict__ st4,   // [Bpairs*5]
    const float4* __restrict__ u4,    // [Bpairs*2]
    float4* __restrict__ out4,        // [Bpairs*5]
    int Bpairs)
{
    int p = blockIdx.x * blockDim.x + threadIdx.x;
    if (p >= Bpairs) return;

    float4 a0 = st4[(size_t)p*5+0], a1 = st4[(size_t)p*5+1], a2 = st4[(size_t)p*5+2],
           a3 = st4[(size_t)p*5+3], a4 = st4[(size_t)p*5+4];
    float4 ua = u4[(size_t)p*2+0], ub = u4[(size_t)p*2+1];

    float q0[5]  = {a0.x, a0.y, a0.z, a0.w, a1.x};
    float qd0[5] = {a1.y, a1.z, a1.w, a2.x, a2.y};
    float q1[5]  = {a2.z, a2.w, a3.x, a3.y, a3.z};
    float qd1[5] = {a3.w, a4.x, a4.y, a4.z, a4.w};

    float x0[5], x1[5];
    solve_row(q0, qd0, ua.x, ua.y, ua.z, ua.w, x0);
    solve_row(q1, qd1, ub.x, ub.y, ub.z, ub.w, x1);

    float4 o0 = {qd0[0], qd0[1], qd0[2], qd0[3]};
    float4 o1 = {qd0[4], x0[0],  x0[1],  x0[2]};
    float4 o2 = {x0[3],  x0[4],  qd1[0], qd1[1]};
    float4 o3 = {qd1[2], qd1[3], qd1[4], x1[0]};
    float4 o4 = {x1[1],  x1[2],  x1[3],  x1[4]};
    out4[(size_t)p*5+0] = o0;
    out4[(size_t)p*5+1] = o1;
    out4[(size_t)p*5+2] = o2;
    out4[(size_t)p*5+3] = o3;
    out4[(size_t)p*5+4] = o4;
}

// Scalar tail for odd B (not hit with B=1e6, kept for safety).
__global__ void amber_dyn_tail(const float* __restrict__ state,
                               const float* __restrict__ u,
                               float* __restrict__ out, int row)
{
    float q[5], qd[5];
    #pragma unroll
    for (int i = 0; i < 5; ++i) { q[i] = state[(size_t)row*10 + i]; qd[i] = state[(size_t)row*10 + 5 + i]; }
    float x[5];
    solve_row(q, qd, u[(size_t)row*4+0], u[(size_t)row*4+1], u[(size_t)row*4+2], u[(size_t)row*4+3], x);
    #pragma unroll
    for (int i = 0; i < 5; ++i) { out[(size_t)row*10 + i] = qd[i]; out[(size_t)row*10 + 5 + i] = x[i]; }
}

extern "C" void kernel_launch(void* const* d_in, const int* in_sizes, int n_in,
                              void* d_out, int out_size, void* d_ws, size_t ws_size,
                              hipStream_t stream) {
    // inputs (setup_inputs order): t [1], state [B*10], u [B*4]
    const float* state = (const float*)d_in[1];
    const float* u     = (const float*)d_in[2];
    float* out = (float*)d_out;
    int B = in_sizes[1] / 10;
    int Bpairs = B / 2;

    int block = 256;
    int grid = (Bpairs + block - 1) / block;
    amber_dyn2<<<grid, block, 0, stream>>>(
        (const float4*)state, (const float4*)u, (float4*)out, Bpairs);

    if (B & 1) {
        amber_dyn_tail<<<1, 1, 0, stream>>>(state, u, out, B - 1);
    }
}

// Round 3
// 21.678 us; speedup vs baseline: 1.2917x; 1.2917x over previous
//
#include <hip/hip_runtime.h>

__device__ __forceinline__ float frcp(float x) { return __builtin_amdgcn_rcpf(x); }

__global__ __launch_bounds__(256) void amber_dyn_kernel(
    const float* __restrict__ state,  // [B,10]
    const float* __restrict__ u,      // [B,4]
    float* __restrict__ out,          // [B,10]
    int B)
{
    int idx = blockIdx.x * blockDim.x + threadIdx.x;
    if (idx >= B) return;

    // ---- load state row (40 B, 8-byte aligned -> float2 x5) ----
    const float2* st2 = reinterpret_cast<const float2*>(state + (size_t)idx * 10);
    float2 r0 = st2[0], r1 = st2[1], r2 = st2[2], r3 = st2[3], r4 = st2[4];
    float q[5]  = {r0.x, r0.y, r1.x, r1.y, r2.x};
    float qd[5] = {r2.y, r3.x, r3.y, r4.x, r4.y};

    // ---- load u row (16 B aligned) ----
    float4 uv = reinterpret_cast<const float4*>(u)[idx];

    // ---- trig ----
    float s[5], c[5];
    #pragma unroll
    for (int i = 0; i < 5; ++i) __sincosf(q[i], &s[i], &c[i]);

    float v2 = qd[0]*qd[0] + qd[1]*qd[1] + qd[2]*qd[2] + qd[3]*qd[3] + qd[4]*qd[4];
    float coef = 0.1f * v2 + 9.8f;

    // r = B@u - H ;  B@u = [0, u0, u1, u2, u3]
    float bu[5] = {0.f, uv.x, uv.y, uv.z, uv.w};
    float r[5];
    #pragma unroll
    for (int i = 0; i < 5; ++i)
        r[i] = bu[i] - (coef * s[i] + 0.05f * qd[i]);

    // ---- Woodbury solve:  D = 2I + 0.3*(c c^T + s s^T)  (rank-2 update)
    //   D^-1 r = 0.5 r - 0.25 * U * M^-1 * (U^T r),  U=[c s],
    //   M = (10/3) I2 + 0.5 * U^T U
    float cc = 0.f, cs = 0.f, pc = 0.f, ps = 0.f;
    #pragma unroll
    for (int i = 0; i < 5; ++i) {
        cc += c[i] * c[i];
        cs += c[i] * s[i];
        pc += c[i] * r[i];
        ps += s[i] * r[i];
    }
    float ss = 5.0f - cc;   // since ci^2 + si^2 = 1

    const float K = 10.0f / 3.0f;
    float m00 = K + 0.5f * cc;
    float m01 = 0.5f * cs;
    float m11 = K + 0.5f * ss;

    float idet = frcp(m00 * m11 - m01 * m01);
    // y = 0.25 * M^-1 * p
    float y0 = 0.25f * idet * (m11 * pc - m01 * ps);
    float y1 = 0.25f * idet * (m00 * ps - m01 * pc);

    float x[5];
    #pragma unroll
    for (int i = 0; i < 5; ++i)
        x[i] = 0.5f * r[i] - (c[i] * y0 + s[i] * y1);

    // ---- store out row: [qd[0..4], x[0..4]] (40 B, 8-byte aligned) ----
    float2* o2 = reinterpret_cast<float2*>(out + (size_t)idx * 10);
    o2[0] = make_float2(qd[0], qd[1]);
    o2[1] = make_float2(qd[2], qd[3]);
    o2[2] = make_float2(qd[4], x[0]);
    o2[3] = make_float2(x[1],  x[2]);
    o2[4] = make_float2(x[3],  x[4]);
}

extern "C" void kernel_launch(void* const* d_in, const int* in_sizes, int n_in,
                              void* d_out, int out_size, void* d_ws, size_t ws_size,
                              hipStream_t stream) {
    // inputs (setup_inputs order): t [1], state [B*10], u [B*4]
    const float* state = (const float*)d_in[1];
    const float* u     = (const float*)d_in[2];
    float* out = (float*)d_out;
    int B = in_sizes[1] / 10;

    int block = 256;
    int grid = (B + block - 1) / block;
    amber_dyn_kernel<<<grid, block, 0, stream>>>(state, u, out, B);
}